// Round 17
// baseline (300.567 us; speedup 1.0000x reference)
//
#include <hip/hip_runtime.h>
#include <math.h>

#define Bb 1024
#define Oo 20
#define Vv 400
#define Ee 840
#define Nn 421            // 1 + Oo + Vv
#define Mm (Bb*Nn)        // 431104
#define Hh 128
#define XST 136           // fallback xh_s row stride (shorts)
#define FMINF (-3.402823466e38f)

// prep kernel grid partition
#define PREP_WCONV 16
#define PREP_CSR   1024
#define PREP_ENC   1684    // Mm*16/512/8, grid-stride x8
#define ENC_STRIDE (PREP_ENC*512)

typedef __attribute__((ext_vector_type(8))) short bf8v;   // 8 bf16 (4 VGPR)
typedef __attribute__((ext_vector_type(4))) float f4v;    // MFMA accumulator

__device__ __forceinline__ float lrelu(float x){ return x > 0.f ? x : 0.2f*x; }
__device__ __forceinline__ float bf2f(unsigned int lo16){
    union { unsigned int u; float f; } v; v.u = lo16 << 16; return v.f;
}
__device__ __forceinline__ float bf2fs(short s){ return bf2f((unsigned short)s); }
__device__ __forceinline__ unsigned short f2bf(float f){
    union { float f; unsigned int u; } v; v.f = f;
    unsigned int u = v.u;
    u += 0x7fffu + ((u >> 16) & 1u);      // round-to-nearest-even
    return (unsigned short)(u >> 16);
}

// ========== PREP: wconv (0..15) | build_csr (16..1039, bitonic) | encode (1040..) ==========
__global__ __launch_bounds__(512) void prep(
    const float* __restrict__ Wg, unsigned short* __restrict__ Wt,
    const int* __restrict__ ei, int* __restrict__ row_ptr, int* __restrict__ colb,
    const float* __restrict__ hn, const float* __restrict__ on, const float* __restrict__ vn,
    const float* __restrict__ Wh, const float* __restrict__ bh,
    const float* __restrict__ Wo, const float* __restrict__ bo,
    const float* __restrict__ Wv, const float* __restrict__ bv,
    unsigned short* __restrict__ x)
{
    __shared__ __align__(16) unsigned char pool[7680];   // csr: keys 4096 + srcL 3360 | enc: Wsh 6144

    const int blk = blockIdx.x;
    const int tid = threadIdx.x;

    if (blk < PREP_WCONV){
        int idx = blk*512 + tid;              // [0, 8192)
        int l = idx >> 12;
        int n = (idx >> 5) & 127;
        int k0 = (idx & 31) * 4;
        #pragma unroll
        for (int q = 0; q < 4; q++){
            int k = k0 + q;
            Wt[(size_t)l*16384 + n*128 + k] = f2bf(Wg[(size_t)l*16384 + k*128 + n]);
        }
        return;
    }
    if (blk < PREP_WCONV + PREP_CSR){
        // ---- build_csr: bitonic sort keys = (dst<<10)|e ; one barrier per (k,j) step ----
        unsigned int* keys = (unsigned int*)pool;         // [1024]
        int*          srcL = (int*)(pool + 4096);         // [840]
        int b = blk - PREP_WCONV;
        const int* eb = ei + (size_t)b*2*Ee;
        for (int e = tid; e < Ee; e += 512){
            srcL[e] = eb[e];
            keys[e] = ((unsigned int)eb[Ee + e] << 10) | (unsigned int)e;
        }
        if (tid < 1024 - Ee) keys[Ee + tid] = 0xFFFFFFFFu;
        __syncthreads();
        for (int k = 2; k <= 1024; k <<= 1){
            for (int j = k >> 1; j > 0; j >>= 1){
                {
                    int i = tid, l = i ^ j;
                    if (l > i){
                        unsigned int a = keys[i], c = keys[l];
                        bool asc = ((i & k) == 0);
                        if (asc ? (a > c) : (a < c)){ keys[i] = c; keys[l] = a; }
                    }
                }
                {
                    int i = tid + 512, l = i ^ j;
                    if (l > i){
                        unsigned int a = keys[i], c = keys[l];
                        bool asc = ((i & k) == 0);
                        if (asc ? (a > c) : (a < c)){ keys[i] = c; keys[l] = a; }
                    }
                }
                __syncthreads();
            }
        }
        for (int i = tid; i < Ee; i += 512){
            unsigned int ky = keys[i];
            int d = (int)(ky >> 10), e = (int)(ky & 1023u);
            colb[b*Ee + i] = srcL[e] | (d << 16);
        }
        if (tid <= Nn){
            unsigned int target = (unsigned int)tid << 10;
            int lo = 0, hi = 1024;
            while (lo < hi){
                int mid = (lo + hi) >> 1;
                if (keys[mid] < target) lo = mid + 1; else hi = mid;
            }
            row_ptr[b*(Nn+1) + tid] = (lo > Ee) ? Ee : lo;
        }
        return;
    }
    // ---- encode -> x [M][128] bf16, row-major; grid-stride x8 ----
    {
        float* Wsh = (float*)pool;                        // [1536]
        if (tid < 256) Wsh[tid] = Wh[tid];
        else           Wsh[tid] = Wo[tid - 256];
        for (int t = tid; t < 640; t += 512) Wsh[512 + t] = Wv[t];
        if (tid < 128){
            Wsh[1152 + tid] = bh[tid];
            Wsh[1280 + tid] = bo[tid];
            Wsh[1408 + tid] = bv[tid];
        }
        __syncthreads();

        int idx0 = (blk - PREP_WCONV - PREP_CSR)*512 + tid;
        #pragma unroll
        for (int it = 0; it < 8; it++){
            int idx = idx0 + it*ENC_STRIDE;               // [0, Mm*16)
            int row = idx >> 4, seg = idx & 15;
            int b = row / Nn;
            int i = row - b*Nn;
            int c = seg*8;
            float acc[8];
            if (i == 0){
                float h0 = hn[b*2], h1 = hn[b*2+1];
                #pragma unroll
                for (int q = 0; q < 8; q++)
                    acc[q] = Wsh[1152 + c + q] + h0*Wsh[c + q] + h1*Wsh[128 + c + q];
            } else if (i < 1 + Oo){
                const float* in = on + ((size_t)b*Oo + (i-1))*2;
                float h0 = in[0], h1 = in[1];
                #pragma unroll
                for (int q = 0; q < 8; q++)
                    acc[q] = Wsh[1280 + c + q] + h0*Wsh[256 + c + q] + h1*Wsh[384 + c + q];
            } else {
                const float* in = vn + ((size_t)b*Vv + (i-1-Oo))*5;
                float v0 = in[0], v1 = in[1], v2 = in[2], v3 = in[3], v4 = in[4];
                #pragma unroll
                for (int q = 0; q < 8; q++){
                    acc[q] = Wsh[1408 + c + q]
                           + v0*Wsh[512 +           c + q] + v1*Wsh[512 + 128 + c + q]
                           + v2*Wsh[512 + 256 + c + q]     + v3*Wsh[512 + 384 + c + q]
                           + v4*Wsh[512 + 512 + c + q];
                }
            }
            uint4 pk;
            pk.x = ((unsigned int)f2bf(fmaxf(acc[1],0.f)) << 16) | f2bf(fmaxf(acc[0],0.f));
            pk.y = ((unsigned int)f2bf(fmaxf(acc[3],0.f)) << 16) | f2bf(fmaxf(acc[2],0.f));
            pk.z = ((unsigned int)f2bf(fmaxf(acc[5],0.f)) << 16) | f2bf(fmaxf(acc[4],0.f));
            pk.w = ((unsigned int)f2bf(fmaxf(acc[7],0.f)) << 16) | f2bf(fmaxf(acc[6],0.f));
            *(uint4*)(x + (size_t)row*Hh + c) = pk;
        }
    }
}

// ================= FAST PATH: one GAT layer, 2 heads (64 ch) per block =================
// r16 body + (A) phase-3 MFMA projection (r11 pattern, barrier-separated)
//           + (B) phase-5 2 lanes/node (32 ch/lane).
// grid 2048 (XCD-chunk swizzled), 512 threads. LDS = 77,824 B -> 2 blocks/CU.
template<bool LAST>
__global__ __launch_bounds__(512,4) void gat_layer(
    const unsigned short* __restrict__ xin,   // [M][128] bf16
    unsigned short* __restrict__ xout,        // [M][128] bf16 (!LAST)
    const unsigned short* __restrict__ Wt,    // [n=128][k=128] bf16, layer-selected
    const float* __restrict__ asr,            // [128] layer-selected
    const float* __restrict__ adt,            // [128]
    const float* __restrict__ bg,             // [128]
    const int* __restrict__ row_ptr,          // [B][422]
    const int* __restrict__ colb,             // [B][840], src|(dst<<16)
    const float* __restrict__ Woff,           // [128]      (LAST)
    const float* __restrict__ Wacc,           // [128][2]   (LAST)
    const float* __restrict__ Wvf,            // [128]      (LAST)
    float* __restrict__ partOff,              // [B][Vv][2] (LAST)
    float* __restrict__ partHead)             // [B][6]     (LAST)
{
    __shared__ unsigned short xh_s[Nn*64];            // 53,888 B, XOR-swizzled
    __shared__ float als_s[Nn*2], ald_s[Nn*2];        //  6,736 B
    __shared__ float as_s[64], ad_s[64], bias_s[64];  //    768 B
    __shared__ __align__(16) unsigned char UPool[16384];  // W_s | {p,pself,colb,rp}

    float* p_s    = (float*)UPool;                    // [840][2]  6,720
    float* pself  = (float*)(UPool + 6720);           // [421][2]  3,368
    int*   colb_s = (int*)  (UPool + 10096);          // [840]     3,360
    int*   rp_s   = (int*)  (UPool + 13456);          // [422]     1,688

    const int lb   = ((int)blockIdx.x & 7)*256 + ((int)blockIdx.x >> 3);
    const int b    = lb >> 1;
    const int half = lb & 1;
    const int chb  = half*64;
    const int tid  = threadIdx.x;
    const size_t base = (size_t)b * Nn;
    const int lane = tid & 63, wave = tid >> 6;
    const int l15 = lane & 15, lhi = lane >> 4;

    #define XH_EL(n_, c_)  xh_s[((n_)<<6) | ((c_) ^ (((n_)&7)<<3))]
    #define XH_CH(n_, c8_) (*(const bf8v*)(xh_s + (((n_)<<6) | (((c8_) ^ ((n_)&7))<<3))))
    #define WS_FRAG(n_, k8_) (*(const bf8v*)((const unsigned short*)UPool + (((n_)<<7) | (((k8_) ^ ((n_)&7))<<3))))

    // ---- phase 1: stage W half swizzled + attn vecs + bias ----
    for (int c = tid; c < 1024; c += 512){
        int n = c >> 4, k8 = c & 15;
        unsigned short* dst = (unsigned short*)UPool + ((n<<7) | ((k8 ^ (n&7))<<3));
        *(uint4*)dst = *(const uint4*)(Wt + (size_t)(chb + n)*Hh + k8*8);
    }
    if (tid < 64)        as_s[tid]       = asr[chb + tid];
    else if (tid < 128)  ad_s[tid-64]    = adt[chb + tid-64];
    else if (tid < 192)  bias_s[tid-128] = bg [chb + tid-128];
    __syncthreads();

    // projection B-fragments: cols {0,1,2,3} = {as_h0, ad_h0, as_h1, ad_h1}, head-masked over K
    bf8v bp0 = {0,0,0,0,0,0,0,0}, bp1 = {0,0,0,0,0,0,0,0};
    {
        const float* avec = (l15 & 1) ? ad_s : as_s;
        if (l15 < 2){
            #pragma unroll
            for (int i = 0; i < 8; i++) bp0[i] = (short)f2bf(avec[lhi*8 + i]);
        } else if (l15 < 4){
            #pragma unroll
            for (int i = 0; i < 8; i++) bp1[i] = (short)f2bf(avec[32 + lhi*8 + i]);
        }
    }

    // ---- phase 2: MFMA GEMM xh[:,chb:chb+64] = x @ W[:,chb:chb+64] (pure) ----
    {
        int rt = wave;
        bf8v afN[4];
        {
            int mrow = (rt<<4) + l15; if (mrow >= Nn) mrow = Nn - 1;
            const unsigned short* xr = xin + (base + mrow)*Hh + lhi*8;
            #pragma unroll
            for (int kc = 0; kc < 4; kc++) afN[kc] = *(const bf8v*)(xr + kc*32);
        }
        while (rt < 27){
            bf8v af[4];
            #pragma unroll
            for (int kc = 0; kc < 4; kc++) af[kc] = afN[kc];
            int rtN = rt + 8;
            if (rtN < 27){
                int mrow = (rtN<<4) + l15; if (mrow >= Nn) mrow = Nn - 1;
                const unsigned short* xr = xin + (base + mrow)*Hh + lhi*8;
                #pragma unroll
                for (int kc = 0; kc < 4; kc++) afN[kc] = *(const bf8v*)(xr + kc*32);
            }
            const int row0 = rt << 4;
            #pragma unroll
            for (int ns = 0; ns < 4; ns++){
                const int nn = ns*16 + l15;
                f4v acc = {0.f,0.f,0.f,0.f};
                #pragma unroll
                for (int kc = 0; kc < 4; kc++)
                    acc = __builtin_amdgcn_mfma_f32_16x16x32_bf16(af[kc], WS_FRAG(nn, kc*4 + lhi), acc, 0,0,0);
                #pragma unroll
                for (int r = 0; r < 4; r++){
                    int m = row0 + lhi*4 + r;
                    if (m < Nn) XH_EL(m, nn) = f2bf(acc[r]);
                }
            }
            rt = rtN;
        }
    }
    __syncthreads();     // xh_s complete; W_s dead

    // ---- phase 3: projection MFMAs (barrier-safe xh reads) + stage colb/rp ----
    for (int rt = wave; rt < 27; rt += 8){
        const int row0 = rt << 4;
        int nr = row0 + l15; if (nr >= Nn) nr = Nn - 1;
        bf8v pa0 = XH_CH(nr, lhi);
        bf8v pa1 = XH_CH(nr, 4 + lhi);
        f4v pac = {0.f,0.f,0.f,0.f};
        pac = __builtin_amdgcn_mfma_f32_16x16x32_bf16(pa0, bp0, pac, 0,0,0);
        pac = __builtin_amdgcn_mfma_f32_16x16x32_bf16(pa1, bp1, pac, 0,0,0);
        if (l15 < 4){
            float* dp = (l15 & 1) ? ald_s : als_s;
            int h2c = l15 >> 1;
            #pragma unroll
            for (int r = 0; r < 4; r++){
                int m = row0 + lhi*4 + r;
                if (m < Nn) dp[m*2 + h2c] = pac[r];
            }
        }
    }
    for (int e = tid; e < Ee; e += 512) colb_s[e] = colb[b*Ee + e];
    for (int i2 = tid; i2 <= Nn; i2 += 512) rp_s[i2] = row_ptr[b*(Nn+1) + i2];
    __syncthreads();

    // ---- phase 4: all exps, flat over edges x heads ----
    for (int idx = tid; idx < Ee*2; idx += 512){
        int e = idx >> 1, h2 = idx & 1;
        int pk = colb_s[e];
        int s = pk & 0xffff, dd = pk >> 16;
        p_s[idx] = __expf(fminf(lrelu(als_s[s*2 + h2] + ald_s[dd*2 + h2]), 60.f));
    }
    for (int idx = tid; idx < Nn*2; idx += 512)
        pself[idx] = __expf(fminf(lrelu(als_s[idx] + ald_s[idx]), 60.f));
    __syncthreads();

    // ---- phase 5: aggregation, 2-lane group per node (32 ch/lane = 1 head) ----
    {
        const int grp = tid >> 1, lane2 = tid & 1;
        const int c80 = lane2*4;              // first of 4 consecutive 8-chunks
        const int ch0 = lane2*32;
        const int h2  = lane2;
        float wof[32];
        if (LAST){
            #pragma unroll
            for (int q = 0; q < 32; q++) wof[q] = Woff[chb + ch0 + q];
        }
        for (int n = grp; n < Nn; n += 256){
            float den = pself[n*2 + h2];
            float a[32];
            {
                bf8v xv0 = XH_CH(n, c80);
                bf8v xv1 = XH_CH(n, c80 + 1);
                bf8v xv2 = XH_CH(n, c80 + 2);
                bf8v xv3 = XH_CH(n, c80 + 3);
                #pragma unroll
                for (int q = 0; q < 8; q++){
                    a[q]      = den * bf2fs(xv0[q]);
                    a[8 + q]  = den * bf2fs(xv1[q]);
                    a[16 + q] = den * bf2fs(xv2[q]);
                    a[24 + q] = den * bf2fs(xv3[q]);
                }
            }
            int rp0 = rp_s[n], rp1 = rp_s[n+1];
            for (int e = rp0; e < rp1; e++){
                int s = colb_s[e] & 0xffff;
                float p = p_s[e*2 + h2];
                bf8v sv0 = XH_CH(s, c80);
                bf8v sv1 = XH_CH(s, c80 + 1);
                bf8v sv2 = XH_CH(s, c80 + 2);
                bf8v sv3 = XH_CH(s, c80 + 3);
                den += p;
                #pragma unroll
                for (int q = 0; q < 8; q++){
                    a[q]      += p * bf2fs(sv0[q]);
                    a[8 + q]  += p * bf2fs(sv1[q]);
                    a[16 + q] += p * bf2fs(sv2[q]);
                    a[24 + q] += p * bf2fs(sv3[q]);
                }
            }
            float inv = 1.f/den;
            float o[32];
            #pragma unroll
            for (int q = 0; q < 32; q++) o[q] = fmaxf(a[q]*inv + bias_s[ch0 + q], 0.f);
            if (!LAST){
                unsigned int pk[16];
                #pragma unroll
                for (int q2 = 0; q2 < 16; q2++)
                    pk[q2] = ((unsigned int)f2bf(o[q2*2+1]) << 16) | f2bf(o[q2*2]);
                unsigned short* dst = xout + (base + n)*Hh + chb + ch0;
                *(uint4*)dst        = make_uint4(pk[0], pk[1], pk[2], pk[3]);
                *(uint4*)(dst + 8)  = make_uint4(pk[4], pk[5], pk[6], pk[7]);
                *(uint4*)(dst + 16) = make_uint4(pk[8], pk[9], pk[10],pk[11]);
                *(uint4*)(dst + 24) = make_uint4(pk[12],pk[13],pk[14],pk[15]);
            } else {
                if (n >= 1 + Oo){
                    float po = 0.f;
                    #pragma unroll
                    for (int q = 0; q < 32; q++) po += o[q]*wof[q];
                    po += __shfl_xor(po, 1);
                    if (lane2 == 0) partOff[((size_t)b*Vv + (n - 1 - Oo))*2 + half] = po;
                } else if (n == 0){
                    float pa0 = 0.f, pa1 = 0.f, pvf = 0.f;
                    #pragma unroll
                    for (int q = 0; q < 32; q++){
                        int gc = chb + ch0 + q;
                        float ov = o[q];
                        pa0 += ov*Wacc[gc*2]; pa1 += ov*Wacc[gc*2+1]; pvf += ov*Wvf[gc];
                    }
                    pa0 += __shfl_xor(pa0, 1);
                    pa1 += __shfl_xor(pa1, 1);
                    pvf += __shfl_xor(pvf, 1);
                    if (lane2 == 0){
                        partHead[b*6 + half*3 + 0] = pa0;
                        partHead[b*6 + half*3 + 1] = pa1;
                        partHead[b*6 + half*3 + 2] = pvf;
                    }
                }
            }
        }
    }
    #undef XH_EL
    #undef XH_CH
    #undef WS_FRAG
}

// ---------------- combine partials -> output ----------------
__global__ __launch_bounds__(128) void heads2(const float* __restrict__ partOff,
    const float* __restrict__ partHead, const float* __restrict__ am,
    const float* __restrict__ bacc, const float* __restrict__ boff,
    const float* __restrict__ bvf, float* __restrict__ out)
{
    int b = blockIdx.x, tid = threadIdx.x;
    float bo = boff[0];
    for (int v = tid; v < Vv; v += 128){
        const float* p = partOff + ((size_t)b*Vv + v)*2;
        out[(size_t)b*403 + 2 + v] = p[0] + p[1] + bo;
    }
    if (tid == 0){
        out[(size_t)b*403 + 0]   = partHead[b*6+0] + partHead[b*6+3] + bacc[0] + fmaxf(logf(am[b*2+0]), FMINF);
        out[(size_t)b*403 + 1]   = partHead[b*6+1] + partHead[b*6+4] + bacc[1] + fmaxf(logf(am[b*2+1]), FMINF);
        out[(size_t)b*403 + 402] = partHead[b*6+2] + partHead[b*6+5] + bvf[0];
    }
}

// ================= FALLBACK (fused kernel, row-major x; used if ws too small) =================
__global__ __launch_bounds__(512) void gat_fused(
    unsigned short* __restrict__ xg,
    const unsigned short* __restrict__ Wt,
    const float* __restrict__ asr, const float* __restrict__ adt,
    const float* __restrict__ bg,
    const int* __restrict__ row_ptr, const int* __restrict__ colb,
    const float* __restrict__ am,
    const float* __restrict__ Wacc, const float* __restrict__ bacc,
    const float* __restrict__ Woff, const float* __restrict__ boff,
    const float* __restrict__ Wvf,  const float* __restrict__ bvf,
    float* __restrict__ out)
{
    __shared__ unsigned short xh_s[Nn][XST];
    __shared__ float als_s[Nn][4];
    __shared__ float ald_s[Nn][4];
    __shared__ float as_s[Hh], ad_s[Hh], bias_s[Hh];
    __shared__ __align__(16) unsigned char UPool[32768];

    float* p_s    = (float*)UPool;
    float* pself  = (float*)(UPool + 13440);
    int*   colb_s = (int*)  (UPool + 20176);
    int*   rp_s   = (int*)  (UPool + 23536);

    const int b   = blockIdx.x;
    const int tid = threadIdx.x;
    const size_t base = (size_t)b * Nn;
    const int lane = tid & 63, wave = tid >> 6;
    const int l15 = lane & 15, lhi = lane >> 4;

    #define BFRAG(n_, kb_) (*(const bf8v*)(UPool + ((n_)<<8) + ((kb_) ^ (((n_)&7)<<4))))

    for (int l = 0; l < 2; l++){
        const unsigned short* Wl = Wt + (size_t)l*16384;
        for (int c = tid; c < 2048; c += 512){
            int n = c >> 4, ck = c & 15;
            int dstb = (n << 8) + ((ck*16) ^ ((n & 7) << 4));
            *(uint4*)(UPool + dstb) = *(const uint4*)(Wl + n*Hh + ck*8);
        }
        if (tid < Hh)        as_s[tid]        = asr[l*Hh + tid];
        else if (tid < 2*Hh) ad_s[tid-Hh]     = adt[l*Hh + tid-Hh];
        else if (tid < 3*Hh) bias_s[tid-2*Hh] = bg [l*Hh + tid-2*Hh];
        __syncthreads();

        {
            int rt = wave;
            bf8v afN[4];
            {
                int mrow = (rt<<4) + l15; if (mrow >= Nn) mrow = Nn - 1;
                const unsigned short* xr = xg + (base + mrow)*Hh + lhi*8;
                #pragma unroll
                for (int kc = 0; kc < 4; kc++) afN[kc] = *(const bf8v*)(xr + kc*32);
            }
            while (rt < 27){
                bf8v af[4];
                #pragma unroll
                for (int kc = 0; kc < 4; kc++) af[kc] = afN[kc];
                int rtN = rt + 8;
                if (rtN < 27){
                    int mrow = (rtN<<4) + l15; if (mrow >= Nn) mrow = Nn - 1;
                    const unsigned short* xr = xg + (base + mrow)*Hh + lhi*8;
                    #pragma unroll
                    for (int kc = 0; kc < 4; kc++) afN[kc] = *(const bf8v*)(xr + kc*32);
                }
                const int row0 = rt << 4;
                #pragma unroll
                for (int ct2 = 0; ct2 < 4; ct2++){
                    const int c0 = ct2*32;
                    const int n0 = c0 + l15, n1 = n0 + 16;
                    f4v acc0 = {0.f,0.f,0.f,0.f}, acc1 = {0.f,0.f,0.f,0.f};
                    #pragma unroll
                    for (int kc = 0; kc < 4; kc++){
                        const int kb = kc*64 + lhi*16;
                        acc0 = __builtin_amdgcn_mfma_f32_16x16x32_bf16(af[kc], BFRAG(n0, kb), acc0, 0,0,0);
                        acc1 = __builtin_amdgcn_mfma_f32_16x16x32_bf16(af[kc], BFRAG(n1, kb), acc1, 0,0,0);
                    }
                    #pragma unroll
                    for (int r = 0; r < 4; r++){
                        int m = row0 + lhi*4 + r;
                        if (m < Nn){
                            xh_s[m][n0] = f2bf(acc0[r]);
                            xh_s[m][n1] = f2bf(acc1[r]);
                        }
                    }
                }
                rt = rtN;
            }
        }
        __syncthreads();

        for (int idx = tid; idx < Nn*4; idx += 512){
            int n = idx >> 2, h = idx & 3;
            const unsigned short* xr = &xh_s[n][h*32];
            float s = 0.f, d = 0.f;
            #pragma unroll
            for (int c4 = 0; c4 < 4; c4++){
                bf8v xv = *(const bf8v*)(xr + c4*8);
                #pragma unroll
                for (int q = 0; q < 8; q++){
                    float xf = bf2fs(xv[q]);
                    s += xf * as_s[h*32 + c4*8 + q];
                    d += xf * ad_s[h*32 + c4*8 + q];
                }
            }
            als_s[n][h] = s; ald_s[n][h] = d;
        }
        for (int e = tid; e < Ee; e += 512) colb_s[e] = colb[b*Ee + e];
        for (int i2 = tid; i2 <= Nn; i2 += 512) rp_s[i2] = row_ptr[b*(Nn+1) + i2];
        __syncthreads();

        for (int idx = tid; idx < Nn*4; idx += 512){
            int n = idx >> 2, h = idx & 3;
            float aldh = ald_s[n][h];
            pself[idx] = __expf(fminf(lrelu(als_s[n][h] + aldh), 60.f));
            int rp0 = rp_s[n], rp1 = rp_s[n+1];
            for (int e = rp0; e < rp1; e++){
                int s = colb_s[e] & 0xffff;
                p_s[e*4 + h] = __expf(fminf(lrelu(als_s[s][h] + aldh), 60.f));
            }
        }
        __syncthreads();

        {
            const int ha  = l15 >> 2;
            const int ch0 = l15 * 8;
            for (int n0 = wave*4; n0 < Nn; n0 += 32){
                int n = n0 + lhi;
                if (n < Nn){
                    float den = pself[n*4 + ha];
                    bf8v xv = *(const bf8v*)&xh_s[n][ch0];
                    float a[8];
                    #pragma unroll
                    for (int q = 0; q < 8; q++) a[q] = den * bf2fs(xv[q]);
                    int rp0 = rp_s[n], rp1 = rp_s[n+1];
                    for (int e = rp0; e < rp1; e++){
                        int s = colb_s[e] & 0xffff;
                        float pC = p_s[e*4 + ha];
                        den += pC;
                        bf8v sv = *(const bf8v*)&xh_s[s][ch0];
                        #pragma unroll
                        for (int q = 0; q < 8; q++) a[q] += pC * bf2fs(sv[q]);
                    }
                    float inv = 1.f/den;
                    unsigned int pk[4];
                    #pragma unroll
                    for (int q2 = 0; q2 < 4; q2++){
                        float o0 = fmaxf(a[q2*2]  *inv + bias_s[ch0 + q2*2],     0.f);
                        float o1 = fmaxf(a[q2*2+1]*inv + bias_s[ch0 + q2*2 + 1], 0.f);
                        pk[q2] = ((unsigned int)f2bf(o1) << 16) | f2bf(o0);
                    }
                    *(uint4*)(xg + (base + n)*Hh + ch0) = make_uint4(pk[0],pk[1],pk[2],pk[3]);
                }
            }
        }
        __syncthreads();
    }

    {
        const int ch0 = l15 * 8;
        for (int v0 = wave*4; v0 < Vv; v0 += 32){
            int v = v0 + lhi;
            if (v < Vv){
                bf8v xv = *(const bf8v*)(xg + (base + 1 + Oo + v)*Hh + ch0);
                float s = 0.f;
                #pragma unroll
                for (int q = 0; q < 8; q++) s += bf2fs(xv[q]) * Woff[ch0 + q];
                s += __shfl_xor(s,1); s += __shfl_xor(s,2);
                s += __shfl_xor(s,4); s += __shfl_xor(s,8);
                if (l15 == 0) out[(size_t)b*403 + 2 + v] = s + boff[0];
            }
        }
        if (wave == 0){
            int k0 = lane*2;
            unsigned int uv = *(const unsigned int*)(xg + base*Hh + k0);
            float x0 = bf2f(uv & 0xffffu), x1 = bf2f(uv >> 16);
            float s0 = x0*Wacc[k0*2]     + x1*Wacc[(k0+1)*2];
            float s1 = x0*Wacc[k0*2 + 1] + x1*Wacc[(k0+1)*2 + 1];
            float s2 = x0*Wvf[k0]        + x1*Wvf[k0+1];
            #pragma unroll
            for (int t = 1; t < 64; t <<= 1){
                s0 += __shfl_xor(s0, t);
                s1 += __shfl_xor(s1, t);
                s2 += __shfl_xor(s2, t);
            }
            if (lane == 0){
                out[(size_t)b*403 + 0]   = s0 + bacc[0] + fmaxf(logf(am[b*2+0]), FMINF);
                out[(size_t)b*403 + 1]   = s1 + bacc[1] + fmaxf(logf(am[b*2+1]), FMINF);
                out[(size_t)b*403 + 402] = s2 + bvf[0];
            }
        }
    }
    #undef BFRAG
}

extern "C" void kernel_launch(void* const* d_in, const int* in_sizes, int n_in,
                              void* d_out, int out_size, void* d_ws, size_t ws_size,
                              hipStream_t stream)
{
    const float* head_node = (const float*)d_in[0];
    const float* obj  = (const float*)d_in[1];
    const float* val  = (const float*)d_in[2];
    const float* am   = (const float*)d_in[3];
    const int*   ei   = (const int*)  d_in[4];
    const float* Weh  = (const float*)d_in[5];
    const float* beh  = (const float*)d_in[6];
    const float* Weo  = (const float*)d_in[7];
    const float* beo  = (const float*)d_in[8];
    const float* Wev  = (const float*)d_in[9];
    const float* bev  = (const float*)d_in[10];
    const float* Wg   = (const float*)d_in[11];
    const float* asr  = (const float*)d_in[12];
    const float* adt  = (const float*)d_in[13];
    const float* bgat = (const float*)d_in[14];
    const float* Wacc = (const float*)d_in[15];
    const float* bacc = (const float*)d_in[16];
    const float* Woff = (const float*)d_in[17];
    const float* boff = (const float*)d_in[18];
    const float* Wvf  = (const float*)d_in[19];
    const float* bvf  = (const float*)d_in[20];

    const size_t xBytes  = (size_t)Mm*Hh*2;            // 110,362,624
    const size_t rpBytes = (size_t)Bb*(Nn+1)*4;        //   1,728,512
    const size_t cbBytes = (size_t)Bb*Ee*4;            //   3,440,640
    const size_t wtBytes = (size_t)2*Hh*Hh*2;          //      65,536
    const size_t poBytes = (size_t)Bb*Vv*2*4;          //   3,276,800
    const size_t phBytes = (size_t)Bb*6*4;             //      24,576
    const size_t needFast = 2*xBytes + rpBytes + cbBytes + wtBytes + poBytes + phBytes;

    char* ws = (char*)d_ws;
    unsigned short* x0 = (unsigned short*)ws;          ws += xBytes;
    const bool fast = (ws_size >= needFast);
    unsigned short* x1 = fast ? (unsigned short*)ws : x0;
    if (fast) ws += xBytes;
    int* row_ptr = (int*)ws;                           ws += rpBytes;
    int* colb    = (int*)ws;                           ws += cbBytes;
    unsigned short* WtB = (unsigned short*)ws;         ws += wtBytes;
    float* partOff  = (float*)ws;                      ws += poBytes;
    float* partHead = (float*)ws;                      ws += phBytes;

    prep<<<PREP_WCONV + PREP_CSR + PREP_ENC, 512, 0, stream>>>(
        Wg, WtB, ei, row_ptr, colb,
        head_node, obj, val, Weh, beh, Weo, beo, Wev, bev, x0);
    if (fast){
        gat_layer<false><<<2048, 512, 0, stream>>>(x0, x1, WtB, asr, adt, bgat,
                                                   row_ptr, colb, Woff, Wacc, Wvf,
                                                   partOff, partHead);
        gat_layer<true><<<2048, 512, 0, stream>>>(x1, x0, WtB + 16384, asr + Hh, adt + Hh, bgat + Hh,
                                                  row_ptr, colb, Woff, Wacc, Wvf,
                                                  partOff, partHead);
        heads2<<<Bb, 128, 0, stream>>>(partOff, partHead, am, bacc, boff, bvf, (float*)d_out);
    } else {
        gat_fused<<<Bb, 512, 0, stream>>>(x0, WtB, asr, adt, bgat, row_ptr, colb,
                                          am, Wacc, bacc, Woff, boff, Wvf, bvf,
                                          (float*)d_out);
    }
}

// Round 18
// 191.297 us; speedup vs baseline: 1.5712x; 1.5712x over previous
//
#include <hip/hip_runtime.h>
#include <math.h>

#define Bb 1024
#define Oo 20
#define Vv 400
#define Ee 840
#define Nn 421            // 1 + Oo + Vv
#define Mm (Bb*Nn)        // 431104
#define Hh 128
#define XST 136           // fallback xh_s row stride (shorts)
#define FMINF (-3.402823466e38f)

// prep kernel grid partition
#define PREP_WCONV 16
#define PREP_CSR   1024
#define PREP_ENC   1684    // Mm*16/512/8, grid-stride x8
#define ENC_STRIDE (PREP_ENC*512)

typedef __attribute__((ext_vector_type(8))) short bf8v;   // 8 bf16 (4 VGPR)
typedef __attribute__((ext_vector_type(4))) float f4v;    // MFMA accumulator

__device__ __forceinline__ float lrelu(float x){ return x > 0.f ? x : 0.2f*x; }
__device__ __forceinline__ float bf2f(unsigned int lo16){
    union { unsigned int u; float f; } v; v.u = lo16 << 16; return v.f;
}
__device__ __forceinline__ float bf2fs(short s){ return bf2f((unsigned short)s); }
__device__ __forceinline__ unsigned short f2bf(float f){
    union { float f; unsigned int u; } v; v.f = f;
    unsigned int u = v.u;
    u += 0x7fffu + ((u >> 16) & 1u);      // round-to-nearest-even
    return (unsigned short)(u >> 16);
}

// ========== PREP: wconv (0..15) | build_csr (16..1039, bitonic) | encode (1040..) ==========
__global__ __launch_bounds__(512) void prep(
    const float* __restrict__ Wg, unsigned short* __restrict__ Wt,
    const int* __restrict__ ei, int* __restrict__ row_ptr, int* __restrict__ colb,
    const float* __restrict__ hn, const float* __restrict__ on, const float* __restrict__ vn,
    const float* __restrict__ Wh, const float* __restrict__ bh,
    const float* __restrict__ Wo, const float* __restrict__ bo,
    const float* __restrict__ Wv, const float* __restrict__ bv,
    unsigned short* __restrict__ x)
{
    __shared__ __align__(16) unsigned char pool[7680];   // csr: keys 4096 + srcL 3360 | enc: Wsh 6144

    const int blk = blockIdx.x;
    const int tid = threadIdx.x;

    if (blk < PREP_WCONV){
        int idx = blk*512 + tid;              // [0, 8192)
        int l = idx >> 12;
        int n = (idx >> 5) & 127;
        int k0 = (idx & 31) * 4;
        #pragma unroll
        for (int q = 0; q < 4; q++){
            int k = k0 + q;
            Wt[(size_t)l*16384 + n*128 + k] = f2bf(Wg[(size_t)l*16384 + k*128 + n]);
        }
        return;
    }
    if (blk < PREP_WCONV + PREP_CSR){
        // ---- build_csr: bitonic sort keys = (dst<<10)|e ; one barrier per (k,j) step ----
        unsigned int* keys = (unsigned int*)pool;         // [1024]
        int*          srcL = (int*)(pool + 4096);         // [840]
        int b = blk - PREP_WCONV;
        const int* eb = ei + (size_t)b*2*Ee;
        for (int e = tid; e < Ee; e += 512){
            srcL[e] = eb[e];
            keys[e] = ((unsigned int)eb[Ee + e] << 10) | (unsigned int)e;
        }
        if (tid < 1024 - Ee) keys[Ee + tid] = 0xFFFFFFFFu;
        __syncthreads();
        for (int k = 2; k <= 1024; k <<= 1){
            for (int j = k >> 1; j > 0; j >>= 1){
                {
                    int i = tid, l = i ^ j;
                    if (l > i){
                        unsigned int a = keys[i], c = keys[l];
                        bool asc = ((i & k) == 0);
                        if (asc ? (a > c) : (a < c)){ keys[i] = c; keys[l] = a; }
                    }
                }
                {
                    int i = tid + 512, l = i ^ j;
                    if (l > i){
                        unsigned int a = keys[i], c = keys[l];
                        bool asc = ((i & k) == 0);
                        if (asc ? (a > c) : (a < c)){ keys[i] = c; keys[l] = a; }
                    }
                }
                __syncthreads();
            }
        }
        for (int i = tid; i < Ee; i += 512){
            unsigned int ky = keys[i];
            int d = (int)(ky >> 10), e = (int)(ky & 1023u);
            colb[b*Ee + i] = srcL[e] | (d << 16);
        }
        if (tid <= Nn){
            unsigned int target = (unsigned int)tid << 10;
            int lo = 0, hi = 1024;
            while (lo < hi){
                int mid = (lo + hi) >> 1;
                if (keys[mid] < target) lo = mid + 1; else hi = mid;
            }
            row_ptr[b*(Nn+1) + tid] = (lo > Ee) ? Ee : lo;
        }
        return;
    }
    // ---- encode -> x [M][128] bf16, row-major; grid-stride x8 ----
    {
        float* Wsh = (float*)pool;                        // [1536]
        if (tid < 256) Wsh[tid] = Wh[tid];
        else           Wsh[tid] = Wo[tid - 256];
        for (int t = tid; t < 640; t += 512) Wsh[512 + t] = Wv[t];
        if (tid < 128){
            Wsh[1152 + tid] = bh[tid];
            Wsh[1280 + tid] = bo[tid];
            Wsh[1408 + tid] = bv[tid];
        }
        __syncthreads();

        int idx0 = (blk - PREP_WCONV - PREP_CSR)*512 + tid;
        #pragma unroll
        for (int it = 0; it < 8; it++){
            int idx = idx0 + it*ENC_STRIDE;               // [0, Mm*16)
            int row = idx >> 4, seg = idx & 15;
            int b = row / Nn;
            int i = row - b*Nn;
            int c = seg*8;
            float acc[8];
            if (i == 0){
                float h0 = hn[b*2], h1 = hn[b*2+1];
                #pragma unroll
                for (int q = 0; q < 8; q++)
                    acc[q] = Wsh[1152 + c + q] + h0*Wsh[c + q] + h1*Wsh[128 + c + q];
            } else if (i < 1 + Oo){
                const float* in = on + ((size_t)b*Oo + (i-1))*2;
                float h0 = in[0], h1 = in[1];
                #pragma unroll
                for (int q = 0; q < 8; q++)
                    acc[q] = Wsh[1280 + c + q] + h0*Wsh[256 + c + q] + h1*Wsh[384 + c + q];
            } else {
                const float* in = vn + ((size_t)b*Vv + (i-1-Oo))*5;
                float v0 = in[0], v1 = in[1], v2 = in[2], v3 = in[3], v4 = in[4];
                #pragma unroll
                for (int q = 0; q < 8; q++){
                    acc[q] = Wsh[1408 + c + q]
                           + v0*Wsh[512 +           c + q] + v1*Wsh[512 + 128 + c + q]
                           + v2*Wsh[512 + 256 + c + q]     + v3*Wsh[512 + 384 + c + q]
                           + v4*Wsh[512 + 512 + c + q];
                }
            }
            uint4 pk;
            pk.x = ((unsigned int)f2bf(fmaxf(acc[1],0.f)) << 16) | f2bf(fmaxf(acc[0],0.f));
            pk.y = ((unsigned int)f2bf(fmaxf(acc[3],0.f)) << 16) | f2bf(fmaxf(acc[2],0.f));
            pk.z = ((unsigned int)f2bf(fmaxf(acc[5],0.f)) << 16) | f2bf(fmaxf(acc[4],0.f));
            pk.w = ((unsigned int)f2bf(fmaxf(acc[7],0.f)) << 16) | f2bf(fmaxf(acc[6],0.f));
            *(uint4*)(x + (size_t)row*Hh + c) = pk;
        }
    }
}

// ================= FAST PATH: one GAT layer, 2 heads (64 ch) per block =================
// r12 golden body; phase-5 = 4 lanes/node (16 ch/lane, r13/r14/r16-validated at 75us).
// grid 2048 (XCD-chunk swizzled), 512 threads. LDS = 77,824 B -> 2 blocks/CU.
template<bool LAST>
__global__ __launch_bounds__(512,4) void gat_layer(
    const unsigned short* __restrict__ xin,   // [M][128] bf16
    unsigned short* __restrict__ xout,        // [M][128] bf16 (!LAST)
    const unsigned short* __restrict__ Wt,    // [n=128][k=128] bf16, layer-selected
    const float* __restrict__ asr,            // [128] layer-selected
    const float* __restrict__ adt,            // [128]
    const float* __restrict__ bg,             // [128]
    const int* __restrict__ row_ptr,          // [B][422]
    const int* __restrict__ colb,             // [B][840], src|(dst<<16)
    const float* __restrict__ Woff,           // [128]      (LAST)
    const float* __restrict__ Wacc,           // [128][2]   (LAST)
    const float* __restrict__ Wvf,            // [128]      (LAST)
    float* __restrict__ partOff,              // [B][Vv][2] (LAST)
    float* __restrict__ partHead)             // [B][6]     (LAST)
{
    __shared__ unsigned short xh_s[Nn*64];            // 53,888 B, XOR-swizzled
    __shared__ float als_s[Nn*2], ald_s[Nn*2];        //  6,736 B
    __shared__ float as_s[64], ad_s[64], bias_s[64];  //    768 B
    __shared__ __align__(16) unsigned char UPool[16384];  // W_s | {p,pself,colb,rp}

    float* p_s    = (float*)UPool;                    // [840][2]  6,720
    float* pself  = (float*)(UPool + 6720);           // [421][2]  3,368
    int*   colb_s = (int*)  (UPool + 10096);          // [840]     3,360
    int*   rp_s   = (int*)  (UPool + 13456);          // [422]     1,688

    const int lb   = ((int)blockIdx.x & 7)*256 + ((int)blockIdx.x >> 3);
    const int b    = lb >> 1;
    const int half = lb & 1;
    const int chb  = half*64;
    const int tid  = threadIdx.x;
    const size_t base = (size_t)b * Nn;
    const int lane = tid & 63, wave = tid >> 6;
    const int l15 = lane & 15, lhi = lane >> 4;

    #define XH_EL(n_, c_)  xh_s[((n_)<<6) | ((c_) ^ (((n_)&7)<<3))]
    #define XH_CH(n_, c8_) (*(const bf8v*)(xh_s + (((n_)<<6) | (((c8_) ^ ((n_)&7))<<3))))
    #define WS_FRAG(n_, k8_) (*(const bf8v*)((const unsigned short*)UPool + (((n_)<<7) | (((k8_) ^ ((n_)&7))<<3))))

    // ---- phase 1: stage W half swizzled + attn vecs + bias ----
    for (int c = tid; c < 1024; c += 512){
        int n = c >> 4, k8 = c & 15;
        unsigned short* dst = (unsigned short*)UPool + ((n<<7) | ((k8 ^ (n&7))<<3));
        *(uint4*)dst = *(const uint4*)(Wt + (size_t)(chb + n)*Hh + k8*8);
    }
    if (tid < 64)        as_s[tid]       = asr[chb + tid];
    else if (tid < 128)  ad_s[tid-64]    = adt[chb + tid-64];
    else if (tid < 192)  bias_s[tid-128] = bg [chb + tid-128];
    __syncthreads();

    // ---- phase 2: MFMA GEMM xh[:,chb:chb+64] = x @ W[:,chb:chb+64] ----
    {
        int rt = wave;
        bf8v afN[4];
        {
            int mrow = (rt<<4) + l15; if (mrow >= Nn) mrow = Nn - 1;
            const unsigned short* xr = xin + (base + mrow)*Hh + lhi*8;
            #pragma unroll
            for (int kc = 0; kc < 4; kc++) afN[kc] = *(const bf8v*)(xr + kc*32);
        }
        while (rt < 27){
            bf8v af[4];
            #pragma unroll
            for (int kc = 0; kc < 4; kc++) af[kc] = afN[kc];
            int rtN = rt + 8;
            if (rtN < 27){
                int mrow = (rtN<<4) + l15; if (mrow >= Nn) mrow = Nn - 1;
                const unsigned short* xr = xin + (base + mrow)*Hh + lhi*8;
                #pragma unroll
                for (int kc = 0; kc < 4; kc++) afN[kc] = *(const bf8v*)(xr + kc*32);
            }
            const int row0 = rt << 4;
            #pragma unroll
            for (int ns = 0; ns < 4; ns++){
                const int nn = ns*16 + l15;
                f4v acc = {0.f,0.f,0.f,0.f};
                #pragma unroll
                for (int kc = 0; kc < 4; kc++)
                    acc = __builtin_amdgcn_mfma_f32_16x16x32_bf16(af[kc], WS_FRAG(nn, kc*4 + lhi), acc, 0,0,0);
                #pragma unroll
                for (int r = 0; r < 4; r++){
                    int m = row0 + lhi*4 + r;
                    if (m < Nn) XH_EL(m, nn) = f2bf(acc[r]);
                }
            }
            rt = rtN;
        }
    }
    __syncthreads();

    // ---- phase 3: scalar projections als/ald; stage colb/rp (W_s dead) ----
    for (int idx = tid; idx < Nn*2; idx += 512){
        int n = idx >> 1, h2 = idx & 1;
        float s = 0.f, d = 0.f;
        #pragma unroll
        for (int j = 0; j < 4; j++){
            bf8v xv = XH_CH(n, h2*4 + j);
            #pragma unroll
            for (int q = 0; q < 8; q++){
                float xf = bf2fs(xv[q]);
                s += xf * as_s[h2*32 + j*8 + q];
                d += xf * ad_s[h2*32 + j*8 + q];
            }
        }
        als_s[idx] = s; ald_s[idx] = d;
    }
    for (int e = tid; e < Ee; e += 512) colb_s[e] = colb[b*Ee + e];
    for (int i2 = tid; i2 <= Nn; i2 += 512) rp_s[i2] = row_ptr[b*(Nn+1) + i2];
    __syncthreads();

    // ---- phase 4: all exps, flat over edges x heads ----
    for (int idx = tid; idx < Ee*2; idx += 512){
        int e = idx >> 1, h2 = idx & 1;
        int pk = colb_s[e];
        int s = pk & 0xffff, dd = pk >> 16;
        p_s[idx] = __expf(fminf(lrelu(als_s[s*2 + h2] + ald_s[dd*2 + h2]), 60.f));
    }
    for (int idx = tid; idx < Nn*2; idx += 512)
        pself[idx] = __expf(fminf(lrelu(als_s[idx] + ald_s[idx]), 60.f));
    __syncthreads();

    // ---- phase 5: aggregation, 4-lane group per node (16 ch/lane) ----
    {
        const int grp = tid >> 2, lane4 = tid & 3;
        const int c80 = lane4*2;
        const int ch0 = lane4*16;
        const int h2  = lane4 >> 1;
        float wof[16];
        if (LAST){
            #pragma unroll
            for (int q = 0; q < 16; q++) wof[q] = Woff[chb + ch0 + q];
        }
        for (int n = grp; n < Nn; n += 128){
            float den = pself[n*2 + h2];
            float a[16];
            {
                bf8v xv0 = XH_CH(n, c80);
                bf8v xv1 = XH_CH(n, c80 + 1);
                #pragma unroll
                for (int q = 0; q < 8; q++){
                    a[q]     = den * bf2fs(xv0[q]);
                    a[8 + q] = den * bf2fs(xv1[q]);
                }
            }
            int rp0 = rp_s[n], rp1 = rp_s[n+1];
            for (int e = rp0; e < rp1; e++){
                int s = colb_s[e] & 0xffff;
                float p = p_s[e*2 + h2];
                bf8v sv0 = XH_CH(s, c80);
                bf8v sv1 = XH_CH(s, c80 + 1);
                den += p;
                #pragma unroll
                for (int q = 0; q < 8; q++){
                    a[q]     += p * bf2fs(sv0[q]);
                    a[8 + q] += p * bf2fs(sv1[q]);
                }
            }
            float inv = 1.f/den;
            float o[16];
            #pragma unroll
            for (int q = 0; q < 16; q++) o[q] = fmaxf(a[q]*inv + bias_s[ch0 + q], 0.f);
            if (!LAST){
                unsigned int pk[8];
                #pragma unroll
                for (int q2 = 0; q2 < 8; q2++)
                    pk[q2] = ((unsigned int)f2bf(o[q2*2+1]) << 16) | f2bf(o[q2*2]);
                unsigned short* dst = xout + (base + n)*Hh + chb + ch0;
                *(uint4*)dst       = make_uint4(pk[0],pk[1],pk[2],pk[3]);
                *(uint4*)(dst + 8) = make_uint4(pk[4],pk[5],pk[6],pk[7]);
            } else {
                if (n >= 1 + Oo){
                    float po = 0.f;
                    #pragma unroll
                    for (int q = 0; q < 16; q++) po += o[q]*wof[q];
                    po += __shfl_xor(po,1); po += __shfl_xor(po,2);
                    if (lane4 == 0) partOff[((size_t)b*Vv + (n - 1 - Oo))*2 + half] = po;
                } else if (n == 0){
                    float pa0 = 0.f, pa1 = 0.f, pvf = 0.f;
                    #pragma unroll
                    for (int q = 0; q < 16; q++){
                        int gc = chb + ch0 + q;
                        float ov = o[q];
                        pa0 += ov*Wacc[gc*2]; pa1 += ov*Wacc[gc*2+1]; pvf += ov*Wvf[gc];
                    }
                    pa0 += __shfl_xor(pa0,1); pa0 += __shfl_xor(pa0,2);
                    pa1 += __shfl_xor(pa1,1); pa1 += __shfl_xor(pa1,2);
                    pvf += __shfl_xor(pvf,1); pvf += __shfl_xor(pvf,2);
                    if (lane4 == 0){
                        partHead[b*6 + half*3 + 0] = pa0;
                        partHead[b*6 + half*3 + 1] = pa1;
                        partHead[b*6 + half*3 + 2] = pvf;
                    }
                }
            }
        }
    }
    #undef XH_EL
    #undef XH_CH
    #undef WS_FRAG
}

// ---------------- combine partials -> output ----------------
__global__ __launch_bounds__(128) void heads2(const float* __restrict__ partOff,
    const float* __restrict__ partHead, const float* __restrict__ am,
    const float* __restrict__ bacc, const float* __restrict__ boff,
    const float* __restrict__ bvf, float* __restrict__ out)
{
    int b = blockIdx.x, tid = threadIdx.x;
    float bo = boff[0];
    for (int v = tid; v < Vv; v += 128){
        const float* p = partOff + ((size_t)b*Vv + v)*2;
        out[(size_t)b*403 + 2 + v] = p[0] + p[1] + bo;
    }
    if (tid == 0){
        out[(size_t)b*403 + 0]   = partHead[b*6+0] + partHead[b*6+3] + bacc[0] + fmaxf(logf(am[b*2+0]), FMINF);
        out[(size_t)b*403 + 1]   = partHead[b*6+1] + partHead[b*6+4] + bacc[1] + fmaxf(logf(am[b*2+1]), FMINF);
        out[(size_t)b*403 + 402] = partHead[b*6+2] + partHead[b*6+5] + bvf[0];
    }
}

// ================= FALLBACK (fused kernel, row-major x; used if ws too small) =================
__global__ __launch_bounds__(512) void gat_fused(
    unsigned short* __restrict__ xg,
    const unsigned short* __restrict__ Wt,
    const float* __restrict__ asr, const float* __restrict__ adt,
    const float* __restrict__ bg,
    const int* __restrict__ row_ptr, const int* __restrict__ colb,
    const float* __restrict__ am,
    const float* __restrict__ Wacc, const float* __restrict__ bacc,
    const float* __restrict__ Woff, const float* __restrict__ boff,
    const float* __restrict__ Wvf,  const float* __restrict__ bvf,
    float* __restrict__ out)
{
    __shared__ unsigned short xh_s[Nn][XST];
    __shared__ float als_s[Nn][4];
    __shared__ float ald_s[Nn][4];
    __shared__ float as_s[Hh], ad_s[Hh], bias_s[Hh];
    __shared__ __align__(16) unsigned char UPool[32768];

    float* p_s    = (float*)UPool;
    float* pself  = (float*)(UPool + 13440);
    int*   colb_s = (int*)  (UPool + 20176);
    int*   rp_s   = (int*)  (UPool + 23536);

    const int b   = blockIdx.x;
    const int tid = threadIdx.x;
    const size_t base = (size_t)b * Nn;
    const int lane = tid & 63, wave = tid >> 6;
    const int l15 = lane & 15, lhi = lane >> 4;

    #define BFRAG(n_, kb_) (*(const bf8v*)(UPool + ((n_)<<8) + ((kb_) ^ (((n_)&7)<<4))))

    for (int l = 0; l < 2; l++){
        const unsigned short* Wl = Wt + (size_t)l*16384;
        for (int c = tid; c < 2048; c += 512){
            int n = c >> 4, ck = c & 15;
            int dstb = (n << 8) + ((ck*16) ^ ((n & 7) << 4));
            *(uint4*)(UPool + dstb) = *(const uint4*)(Wl + n*Hh + ck*8);
        }
        if (tid < Hh)        as_s[tid]        = asr[l*Hh + tid];
        else if (tid < 2*Hh) ad_s[tid-Hh]     = adt[l*Hh + tid-Hh];
        else if (tid < 3*Hh) bias_s[tid-2*Hh] = bg [l*Hh + tid-2*Hh];
        __syncthreads();

        {
            int rt = wave;
            bf8v afN[4];
            {
                int mrow = (rt<<4) + l15; if (mrow >= Nn) mrow = Nn - 1;
                const unsigned short* xr = xg + (base + mrow)*Hh + lhi*8;
                #pragma unroll
                for (int kc = 0; kc < 4; kc++) afN[kc] = *(const bf8v*)(xr + kc*32);
            }
            while (rt < 27){
                bf8v af[4];
                #pragma unroll
                for (int kc = 0; kc < 4; kc++) af[kc] = afN[kc];
                int rtN = rt + 8;
                if (rtN < 27){
                    int mrow = (rtN<<4) + l15; if (mrow >= Nn) mrow = Nn - 1;
                    const unsigned short* xr = xg + (base + mrow)*Hh + lhi*8;
                    #pragma unroll
                    for (int kc = 0; kc < 4; kc++) afN[kc] = *(const bf8v*)(xr + kc*32);
                }
                const int row0 = rt << 4;
                #pragma unroll
                for (int ct2 = 0; ct2 < 4; ct2++){
                    const int c0 = ct2*32;
                    const int n0 = c0 + l15, n1 = n0 + 16;
                    f4v acc0 = {0.f,0.f,0.f,0.f}, acc1 = {0.f,0.f,0.f,0.f};
                    #pragma unroll
                    for (int kc = 0; kc < 4; kc++){
                        const int kb = kc*64 + lhi*16;
                        acc0 = __builtin_amdgcn_mfma_f32_16x16x32_bf16(af[kc], BFRAG(n0, kb), acc0, 0,0,0);
                        acc1 = __builtin_amdgcn_mfma_f32_16x16x32_bf16(af[kc], BFRAG(n1, kb), acc1, 0,0,0);
                    }
                    #pragma unroll
                    for (int r = 0; r < 4; r++){
                        int m = row0 + lhi*4 + r;
                        if (m < Nn){
                            xh_s[m][n0] = f2bf(acc0[r]);
                            xh_s[m][n1] = f2bf(acc1[r]);
                        }
                    }
                }
                rt = rtN;
            }
        }
        __syncthreads();

        for (int idx = tid; idx < Nn*4; idx += 512){
            int n = idx >> 2, h = idx & 3;
            const unsigned short* xr = &xh_s[n][h*32];
            float s = 0.f, d = 0.f;
            #pragma unroll
            for (int c4 = 0; c4 < 4; c4++){
                bf8v xv = *(const bf8v*)(xr + c4*8);
                #pragma unroll
                for (int q = 0; q < 8; q++){
                    float xf = bf2fs(xv[q]);
                    s += xf * as_s[h*32 + c4*8 + q];
                    d += xf * ad_s[h*32 + c4*8 + q];
                }
            }
            als_s[n][h] = s; ald_s[n][h] = d;
        }
        for (int e = tid; e < Ee; e += 512) colb_s[e] = colb[b*Ee + e];
        for (int i2 = tid; i2 <= Nn; i2 += 512) rp_s[i2] = row_ptr[b*(Nn+1) + i2];
        __syncthreads();

        for (int idx = tid; idx < Nn*4; idx += 512){
            int n = idx >> 2, h = idx & 3;
            float aldh = ald_s[n][h];
            pself[idx] = __expf(fminf(lrelu(als_s[n][h] + aldh), 60.f));
            int rp0 = rp_s[n], rp1 = rp_s[n+1];
            for (int e = rp0; e < rp1; e++){
                int s = colb_s[e] & 0xffff;
                p_s[e*4 + h] = __expf(fminf(lrelu(als_s[s][h] + aldh), 60.f));
            }
        }
        __syncthreads();

        {
            const int ha  = l15 >> 2;
            const int ch0 = l15 * 8;
            for (int n0 = wave*4; n0 < Nn; n0 += 32){
                int n = n0 + lhi;
                if (n < Nn){
                    float den = pself[n*4 + ha];
                    bf8v xv = *(const bf8v*)&xh_s[n][ch0];
                    float a[8];
                    #pragma unroll
                    for (int q = 0; q < 8; q++) a[q] = den * bf2fs(xv[q]);
                    int rp0 = rp_s[n], rp1 = rp_s[n+1];
                    for (int e = rp0; e < rp1; e++){
                        int s = colb_s[e] & 0xffff;
                        float pC = p_s[e*4 + ha];
                        den += pC;
                        bf8v sv = *(const bf8v*)&xh_s[s][ch0];
                        #pragma unroll
                        for (int q = 0; q < 8; q++) a[q] += pC * bf2fs(sv[q]);
                    }
                    float inv = 1.f/den;
                    unsigned int pk[4];
                    #pragma unroll
                    for (int q2 = 0; q2 < 4; q2++){
                        float o0 = fmaxf(a[q2*2]  *inv + bias_s[ch0 + q2*2],     0.f);
                        float o1 = fmaxf(a[q2*2+1]*inv + bias_s[ch0 + q2*2 + 1], 0.f);
                        pk[q2] = ((unsigned int)f2bf(o1) << 16) | f2bf(o0);
                    }
                    *(uint4*)(xg + (base + n)*Hh + ch0) = make_uint4(pk[0],pk[1],pk[2],pk[3]);
                }
            }
        }
        __syncthreads();
    }

    {
        const int ch0 = l15 * 8;
        for (int v0 = wave*4; v0 < Vv; v0 += 32){
            int v = v0 + lhi;
            if (v < Vv){
                bf8v xv = *(const bf8v*)(xg + (base + 1 + Oo + v)*Hh + ch0);
                float s = 0.f;
                #pragma unroll
                for (int q = 0; q < 8; q++) s += bf2fs(xv[q]) * Woff[ch0 + q];
                s += __shfl_xor(s,1); s += __shfl_xor(s,2);
                s += __shfl_xor(s,4); s += __shfl_xor(s,8);
                if (l15 == 0) out[(size_t)b*403 + 2 + v] = s + boff[0];
            }
        }
        if (wave == 0){
            int k0 = lane*2;
            unsigned int uv = *(const unsigned int*)(xg + base*Hh + k0);
            float x0 = bf2f(uv & 0xffffu), x1 = bf2f(uv >> 16);
            float s0 = x0*Wacc[k0*2]     + x1*Wacc[(k0+1)*2];
            float s1 = x0*Wacc[k0*2 + 1] + x1*Wacc[(k0+1)*2 + 1];
            float s2 = x0*Wvf[k0]        + x1*Wvf[k0+1];
            #pragma unroll
            for (int t = 1; t < 64; t <<= 1){
                s0 += __shfl_xor(s0, t);
                s1 += __shfl_xor(s1, t);
                s2 += __shfl_xor(s2, t);
            }
            if (lane == 0){
                out[(size_t)b*403 + 0]   = s0 + bacc[0] + fmaxf(logf(am[b*2+0]), FMINF);
                out[(size_t)b*403 + 1]   = s1 + bacc[1] + fmaxf(logf(am[b*2+1]), FMINF);
                out[(size_t)b*403 + 402] = s2 + bvf[0];
            }
        }
    }
    #undef BFRAG
}

extern "C" void kernel_launch(void* const* d_in, const int* in_sizes, int n_in,
                              void* d_out, int out_size, void* d_ws, size_t ws_size,
                              hipStream_t stream)
{
    const float* head_node = (const float*)d_in[0];
    const float* obj  = (const float*)d_in[1];
    const float* val  = (const float*)d_in[2];
    const float* am   = (const float*)d_in[3];
    const int*   ei   = (const int*)  d_in[4];
    const float* Weh  = (const float*)d_in[5];
    const float* beh  = (const float*)d_in[6];
    const float* Weo  = (const float*)d_in[7];
    const float* beo  = (const float*)d_in[8];
    const float* Wev  = (const float*)d_in[9];
    const float* bev  = (const float*)d_in[10];
    const float* Wg   = (const float*)d_in[11];
    const float* asr  = (const float*)d_in[12];
    const float* adt  = (const float*)d_in[13];
    const float* bgat = (const float*)d_in[14];
    const float* Wacc = (const float*)d_in[15];
    const float* bacc = (const float*)d_in[16];
    const float* Woff = (const float*)d_in[17];
    const float* boff = (const float*)d_in[18];
    const float* Wvf  = (const float*)d_in[19];
    const float* bvf  = (const float*)d_in[20];

    const size_t xBytes  = (size_t)Mm*Hh*2;            // 110,362,624
    const size_t rpBytes = (size_t)Bb*(Nn+1)*4;        //   1,728,512
    const size_t cbBytes = (size_t)Bb*Ee*4;            //   3,440,640
    const size_t wtBytes = (size_t)2*Hh*Hh*2;          //      65,536
    const size_t poBytes = (size_t)Bb*Vv*2*4;          //   3,276,800
    const size_t phBytes = (size_t)Bb*6*4;             //      24,576
    const size_t needFast = 2*xBytes + rpBytes + cbBytes + wtBytes + poBytes + phBytes;

    char* ws = (char*)d_ws;
    unsigned short* x0 = (unsigned short*)ws;          ws += xBytes;
    const bool fast = (ws_size >= needFast);
    unsigned short* x1 = fast ? (unsigned short*)ws : x0;
    if (fast) ws += xBytes;
    int* row_ptr = (int*)ws;                           ws += rpBytes;
    int* colb    = (int*)ws;                           ws += cbBytes;
    unsigned short* WtB = (unsigned short*)ws;         ws += wtBytes;
    float* partOff  = (float*)ws;                      ws += poBytes;
    float* partHead = (float*)ws;                      ws += phBytes;

    prep<<<PREP_WCONV + PREP_CSR + PREP_ENC, 512, 0, stream>>>(
        Wg, WtB, ei, row_ptr, colb,
        head_node, obj, val, Weh, beh, Weo, beo, Wev, bev, x0);
    if (fast){
        gat_layer<false><<<2048, 512, 0, stream>>>(x0, x1, WtB, asr, adt, bgat,
                                                   row_ptr, colb, Woff, Wacc, Wvf,
                                                   partOff, partHead);
        gat_layer<true><<<2048, 512, 0, stream>>>(x1, x0, WtB + 16384, asr + Hh, adt + Hh, bgat + Hh,
                                                  row_ptr, colb, Woff, Wacc, Wvf,
                                                  partOff, partHead);
        heads2<<<Bb, 128, 0, stream>>>(partOff, partHead, am, bacc, boff, bvf, (float*)d_out);
    } else {
        gat_fused<<<Bb, 512, 0, stream>>>(x0, WtB, asr, adt, bgat, row_ptr, colb,
                                          am, Wacc, bacc, Woff, boff, Wvf, bvf,
                                          (float*)d_out);
    }
}